// Round 12
// baseline (570.214 us; speedup 1.0000x reference)
//
#include <hip/hip_runtime.h>
#include <stdint.h>

#define M_DIM 8192
#define N_DIM 11008
#define K_DIM 4096

#define BM 256
#define BN 256
#define BK 64                    // i8: 64 B per row per tile
#define NT (K_DIM / BK)          // 64 K-tiles
#define GRID_M (M_DIM / BM)      // 32
#define GRID_N (N_DIM / BN)      // 43
#define NWG (GRID_M * GRID_N)    // 1376 (divisible by 8)

#define BUF (BM * BK)            // 16384 B per A tile-buffer
#define NRING 5                  // A-only ring-5: LDS = 5*16384 = 80 KiB

typedef int i32x4 __attribute__((ext_vector_type(4)));

__device__ __forceinline__ void gload16(const int8_t* src, int8_t* dst) {
    __builtin_amdgcn_global_load_lds(
        (const __attribute__((address_space(1))) uint32_t*)src,
        (__attribute__((address_space(3))) uint32_t*)dst, 16, 0, 0);
}

// async 16B global->VGPR load; NO compiler wait is generated for asm results,
// so every consumer is guarded by a manual counted vmcnt + sched_barrier(0).
__device__ __forceinline__ i32x4 bload(const int8_t* base, uint32_t voff) {
    i32x4 r;
    asm volatile("global_load_dwordx4 %0, %1, %2"
                 : "=v"(r) : "v"(voff), "s"(base) : "memory");
    return r;
}

// ---------- pre-pass 1: per-row (token) absmax quant of x -> i8 + inv scale ----------

__global__ __launch_bounds__(256) void quant_x_kernel(
    const float* __restrict__ x, int8_t* __restrict__ xq, float* __restrict__ sinv)
{
    const int wave = blockIdx.x * 4 + (threadIdx.x >> 6);
    const int lane = threadIdx.x & 63;
    const float* row = x + (size_t)wave * K_DIM;

    float4 v[16];
    float mx = 0.0f;
    #pragma unroll
    for (int j = 0; j < 16; ++j) {
        v[j] = *(const float4*)(row + (j * 64 + lane) * 4);
        mx = fmaxf(mx, fmaxf(fmaxf(fabsf(v[j].x), fabsf(v[j].y)),
                             fmaxf(fabsf(v[j].z), fabsf(v[j].w))));
    }
    #pragma unroll
    for (int off = 32; off > 0; off >>= 1)
        mx = fmaxf(mx, __shfl_xor(mx, off));
    if (mx < 1e-30f) mx = 1e-30f;
    const float s = 127.0f / mx;

    int8_t* orow = xq + (size_t)wave * K_DIM;
    #pragma unroll
    for (int j = 0; j < 16; ++j) {
        int a = (int)__builtin_rintf(v[j].x * s);
        int b = (int)__builtin_rintf(v[j].y * s);
        int c = (int)__builtin_rintf(v[j].z * s);
        int d = (int)__builtin_rintf(v[j].w * s);
        uint32_t p = (uint32_t)(a & 0xFF) | ((uint32_t)(b & 0xFF) << 8) |
                     ((uint32_t)(c & 0xFF) << 16) | ((uint32_t)(d & 0xFF) << 24);
        *(uint32_t*)(orow + (j * 64 + lane) * 4) = p;
    }
    if (lane == 0) sinv[wave] = mx / 127.0f;
}

// ---------- pre-pass 2: f32 w -> sign(w) in i8 (exact {-1,0,+1}) ----------

__global__ __launch_bounds__(256) void sign_w_kernel(
    const float* __restrict__ w, int8_t* __restrict__ wq, long long n16)
{
    long long i = (long long)blockIdx.x * blockDim.x + threadIdx.x;
    const long long stride = (long long)gridDim.x * blockDim.x;
    for (; i < n16; i += stride) {
        const float* src = w + i * 16;
        uint32_t pk[4];
        #pragma unroll
        for (int q = 0; q < 4; ++q) {
            float4 f = *(const float4*)(src + q * 4);
            int a = (f.x > 0.f) ? 1 : ((f.x < 0.f) ? -1 : 0);
            int b = (f.y > 0.f) ? 1 : ((f.y < 0.f) ? -1 : 0);
            int c = (f.z > 0.f) ? 1 : ((f.z < 0.f) ? -1 : 0);
            int d = (f.w > 0.f) ? 1 : ((f.w < 0.f) ? -1 : 0);
            pk[q] = (uint32_t)(a & 0xFF) | ((uint32_t)(b & 0xFF) << 8) |
                    ((uint32_t)(c & 0xFF) << 16) | ((uint32_t)(d & 0xFF) << 24);
        }
        *(i32x4*)(wq + i * 16) = (i32x4){(int)pk[0], (int)pk[1], (int)pk[2], (int)pk[3]};
    }
}

// ---------- main GEMM (i8): 256x256, BK=64, 8 waves.
// r11 post-mortem: four schedule variants all hit the DS+MFMA serial sum ->
// the DS PIPE was the contended resource (96 ds_read_b128 = 1152 cy + 32
// gload-LDS-writes ~200 cy >= MFMA 1306 cy per tile per CU). Fix: B-fragments
// load DIRECTLY from global (row-major [N][K] delivers the exact per-lane
// MFMA B operand; each frag used by only 2 waves -> L2 absorbs the reuse,
// helped by the XCD swizzle grouping same-bn blocks). DS now A-only:
// 64 reads + 16 DMA writes ~ 900 cy < MFMA 1306 cy.
//
// VMEM stream per body (in-order): [G0: bfrag(t+1) x4][G2: stageA(t+4) x2].
// Steady-state invariant at G0(t) pre-wait: [st(t+2)x2, bfrag(t)x4, st(t+3)x2]
// -> vmcnt(2) drains bfrag(t) (RAW for this body's MFMAs) AND st(t+2)
// (cross-wave RAW: drained per-wave before barrier(t), read in body(t+1)).
// Tail: t>=NT-3 -> vmcnt(0) (cheap: bfrag issued a full body earlier).
// Boundary: s_barrier only. A-slot WAR: wave's reads of tile tau complete
// (compiler lgkm before last MFMA use) before barrier(tau); next writer
// stage(tau+5) issues at G2(tau+1) after that barrier. Ring-5 slack ~3 tiles.

__global__ __launch_bounds__(512, 2) void ternary_gemm_i8(
    const int8_t* __restrict__ A, const int8_t* __restrict__ B,
    const float* __restrict__ bias, const float* __restrict__ sinv,
    float* __restrict__ out)
{
    extern __shared__ int8_t lds[];
    int8_t* As = lds;                   // [NRING][BUF]

    const int tid  = threadIdx.x;
    const int lane = tid & 63;
    const int wid  = tid >> 6;        // 0..7
    const int wm   = wid >> 2;        // 0..1
    const int wn   = wid & 3;         // 0..3
    const int l15  = lane & 15;
    const int l4   = lane >> 4;       // 0..3

    // T1: bijective XCD swizzle (NWG % 8 == 0), bn-minor for L2 reuse
    const int bid = blockIdx.x;
    const int swz = (bid & 7) * (NWG / 8) + (bid >> 3);
    const int bm  = swz / GRID_N;
    const int bn  = swz % GRID_N;
    const long brow = (long)bm * BM;
    const long bcol = (long)bn * BN;

    // ---- A staging addressing (r6-verified): inst r covers rows r*128+(tid>>2),
    // 16B-slot tid&3; LDS dest linear; global src slot inverse-swizzled ----
    const int rowt = tid >> 2;                        // 0..127
    const int ssrc = (tid & 3) ^ ((tid >> 3) & 3);
    const int8_t* pA = A + (size_t)(brow + rowt) * K_DIM + ssrc * 16;

    auto stageA2 = [&](int t, int bslot) {
        #pragma unroll
        for (int r = 0; r < 2; ++r)
            gload16(pA + (size_t)r * 128 * K_DIM + (size_t)t * BK,
                    As + bslot * BUF + r * 8192 + wid * 1024 + (lane << 4));
    };

    // ---- A fragment read addressing (r6-verified swizzle) ----
    const int slot = l4 ^ ((l15 >> 1) & 3);
    const int aOff = (wm * 16 + l15) * 64 + slot * 16;   // + m*2048

    // ---- B fragment direct-global addressing: per-lane 32-bit voffset ----
    // frag n covers cols bcol + n*64 + wn*16 + [0,16): lane l -> col +(l&15),
    // k = t*64 + (l>>4)*16. voff advances by 64 per tile.
    uint32_t vb[4];
    #pragma unroll
    for (int n = 0; n < 4; ++n)
        vb[n] = (uint32_t)(((uint32_t)(bcol + n * 64 + wn * 16 + l15)) * (uint32_t)K_DIM
                           + (uint32_t)(l4 * 16));

    i32x4 acc[8][4];
    #pragma unroll
    for (int m = 0; m < 8; ++m)
        #pragma unroll
        for (int n = 0; n < 4; ++n) acc[m][n] = (i32x4){0, 0, 0, 0};

    i32x4 arA[8], brA[4], arB[8], brB[4];

    // ---- prologue: bfrag(0) x4; stage A tiles 0..3 (8 gloads); vmcnt(4)
    // [drains bfrag0 + st0 + st1, leaves st2,st3]; barrier; A-frags(0) ----
    #pragma unroll
    for (int n = 0; n < 4; ++n) { brA[n] = bload(B, vb[n]); vb[n] += 64; }
    stageA2(0, 0); stageA2(1, 1); stageA2(2, 2); stageA2(3, 3);
    asm volatile("s_waitcnt vmcnt(4)" ::: "memory");
    __builtin_amdgcn_s_barrier();
    __builtin_amdgcn_sched_barrier(0);
    #pragma unroll
    for (int m = 0; m < 8; ++m) arA[m] = *(const i32x4*)(As + m * 2048 + aOff);
    __builtin_amdgcn_sched_barrier(0);

    int sn = 1;   // ring slot of tile t+1 (A reads)
    int ss = 4;   // ring slot of tile t+4 (A stage)

    auto body = [&](int t, i32x4 (&arc)[8], i32x4 (&brc)[4],
                           i32x4 (&arn)[8], i32x4 (&brn)[4]) {
        const int8_t* An = As + sn * BUF;
        const bool rd = (t + 1 < NT);
        const bool st = (t + 4 < NT);

        // ---- G0: certify bfrag(t) [+ st(t+2) for next barrier]; MFMA m0,m1;
        //          issue bfrag(t+1); A-reads arn[0,1] ----
        if (t <= NT - 4) { asm volatile("s_waitcnt vmcnt(2)" ::: "memory"); }
        else             { asm volatile("s_waitcnt vmcnt(0)" ::: "memory"); }
        __builtin_amdgcn_sched_barrier(0);
        __builtin_amdgcn_s_setprio(1);
        #pragma unroll
        for (int m = 0; m < 2; ++m)
            #pragma unroll
            for (int n = 0; n < 4; ++n)
                acc[m][n] = __builtin_amdgcn_mfma_i32_16x16x64_i8(arc[m], brc[n], acc[m][n], 0, 0, 0);
        __builtin_amdgcn_s_setprio(0);
        if (rd) {
            #pragma unroll
            for (int n = 0; n < 4; ++n) { brn[n] = bload(B, vb[n]); vb[n] += 64; }
            arn[0] = *(const i32x4*)(An + 0 * 2048 + aOff);
            arn[1] = *(const i32x4*)(An + 1 * 2048 + aOff);
        }
        __builtin_amdgcn_sched_barrier(0);

        // ---- G1: MFMA m2,m3 ; arn[2,3] ----
        __builtin_amdgcn_s_setprio(1);
        #pragma unroll
        for (int m = 2; m < 4; ++m)
            #pragma unroll
            for (int n = 0; n < 4; ++n)
                acc[m][n] = __builtin_amdgcn_mfma_i32_16x16x64_i8(arc[m], brc[n], acc[m][n], 0, 0, 0);
        __builtin_amdgcn_s_setprio(0);
        if (rd) {
            arn[2] = *(const i32x4*)(An + 2 * 2048 + aOff);
            arn[3] = *(const i32x4*)(An + 3 * 2048 + aOff);
        }
        __builtin_amdgcn_sched_barrier(0);

        // ---- G2: MFMA m4,m5 ; arn[4,5] ; stage A(t+4) ----
        __builtin_amdgcn_s_setprio(1);
        #pragma unroll
        for (int m = 4; m < 6; ++m)
            #pragma unroll
            for (int n = 0; n < 4; ++n)
                acc[m][n] = __builtin_amdgcn_mfma_i32_16x16x64_i8(arc[m], brc[n], acc[m][n], 0, 0, 0);
        __builtin_amdgcn_s_setprio(0);
        if (rd) {
            arn[4] = *(const i32x4*)(An + 4 * 2048 + aOff);
            arn[5] = *(const i32x4*)(An + 5 * 2048 + aOff);
        }
        if (st) stageA2(t + 4, ss);
        __builtin_amdgcn_sched_barrier(0);

        // ---- G3: MFMA m6,m7 ; arn[6,7] ----
        __builtin_amdgcn_s_setprio(1);
        #pragma unroll
        for (int m = 6; m < 8; ++m)
            #pragma unroll
            for (int n = 0; n < 4; ++n)
                acc[m][n] = __builtin_amdgcn_mfma_i32_16x16x64_i8(arc[m], brc[n], acc[m][n], 0, 0, 0);
        __builtin_amdgcn_s_setprio(0);
        if (rd) {
            arn[6] = *(const i32x4*)(An + 6 * 2048 + aOff);
            arn[7] = *(const i32x4*)(An + 7 * 2048 + aOff);
        }
        __builtin_amdgcn_sched_barrier(0);

        // ---- tile boundary: barrier only ----
        __builtin_amdgcn_s_barrier();
        __builtin_amdgcn_sched_barrier(0);

        sn = (sn == NRING - 1) ? 0 : sn + 1;
        ss = (ss == NRING - 1) ? 0 : ss + 1;
    };

    for (int t = 0; t < NT; t += 2) {
        body(t,     arA, brA, arB, brB);
        body(t + 1, arB, brB, arA, brA);
    }

    // ---- epilogue: out = acc * sinv[row] + bias[col] ----
    // C/D layout (dtype-independent, m121-128): col=lane&15, row=(lane>>4)*4+reg
    int   cols[4];
    float bv[4];
    #pragma unroll
    for (int n = 0; n < 4; ++n) {
        cols[n] = (int)bcol + n * 64 + wn * 16 + l15;
        bv[n] = bias[cols[n]];
    }
    #pragma unroll
    for (int m = 0; m < 8; ++m) {
        const size_t row0 = (size_t)brow + m * 32 + wm * 16 + l4 * 4;
        float s0 = sinv[row0], s1 = sinv[row0 + 1], s2 = sinv[row0 + 2], s3 = sinv[row0 + 3];
        #pragma unroll
        for (int n = 0; n < 4; ++n) {
            out[(row0 + 0) * N_DIM + cols[n]] = (float)acc[m][n][0] * s0 + bv[n];
            out[(row0 + 1) * N_DIM + cols[n]] = (float)acc[m][n][1] * s1 + bv[n];
            out[(row0 + 2) * N_DIM + cols[n]] = (float)acc[m][n][2] * s2 + bv[n];
            out[(row0 + 3) * N_DIM + cols[n]] = (float)acc[m][n][3] * s3 + bv[n];
        }
    }
}

// ---------- fallback (only if workspace too small): correct but slow ----------

__global__ void naive_kernel(const float* __restrict__ x, const float* __restrict__ w,
                             const float* __restrict__ bias, float* __restrict__ out) {
    long long o = (long long)blockIdx.x * blockDim.x + threadIdx.x;
    if (o >= (long long)M_DIM * N_DIM) return;
    int row = (int)(o / N_DIM), col = (int)(o % N_DIM);
    float s = 0.0f;
    const float* xr = x + (size_t)row * K_DIM;
    const float* wr = w + (size_t)col * K_DIM;
    for (int k = 0; k < K_DIM; ++k) {
        float wv = wr[k];
        s += (wv > 0.0f) ? xr[k] : ((wv < 0.0f) ? -xr[k] : 0.0f);
    }
    out[o] = s + bias[col];
}

// ---------- launch ----------

extern "C" void kernel_launch(void* const* d_in, const int* in_sizes, int n_in,
                              void* d_out, int out_size, void* d_ws, size_t ws_size,
                              hipStream_t stream) {
    const float* x    = (const float*)d_in[0];
    const float* w    = (const float*)d_in[1];
    const float* bias = (const float*)d_in[2];
    float* out        = (float*)d_out;

    const size_t xq_bytes = (size_t)M_DIM * K_DIM;        // 33.6 MB
    const size_t wq_bytes = (size_t)N_DIM * K_DIM;        // 45.1 MB
    const size_t si_bytes = (size_t)M_DIM * sizeof(float);

    if (ws_size >= xq_bytes + wq_bytes + si_bytes) {
        int8_t* xq   = (int8_t*)d_ws;
        int8_t* wq   = (int8_t*)((char*)d_ws + xq_bytes);
        float*  sinv = (float*)((char*)d_ws + xq_bytes + wq_bytes);

        quant_x_kernel<<<M_DIM / 4, 256, 0, stream>>>(x, xq, sinv);
        const long long n16 = ((long long)N_DIM * K_DIM) / 16;
        sign_w_kernel<<<2048, 256, 0, stream>>>(w, wq, n16);

        const int lds_bytes = NRING * BUF;   // 81920
        hipFuncSetAttribute(reinterpret_cast<const void*>(ternary_gemm_i8),
                            hipFuncAttributeMaxDynamicSharedMemorySize, lds_bytes);
        ternary_gemm_i8<<<NWG, 512, lds_bytes, stream>>>(xq, wq, bias, sinv, out);
    } else {
        const long long total = (long long)M_DIM * N_DIM;
        naive_kernel<<<(int)((total + 255) / 256), 256, 0, stream>>>(x, w, bias, out);
    }
}